// Round 6
// baseline (612.895 us; speedup 1.0000x reference)
//
#include <hip/hip_runtime.h>
#include <hip/hip_bf16.h>
#include <math.h>

// Problem constants (fixed by the reference).
#define N_ROWS   8192
#define K_CODES  8192
#define H_DIM    256
#define NSPLIT   8
#define KSPLIT   (K_CODES / NSPLIT)   // 1024 codes per block-column (4 ct tiles of 256)
#define MARGIN   5e-4f                // bf16-split dot err ~2e-5; 20x safety

typedef short short8 __attribute__((ext_vector_type(8)));
typedef float f32x4  __attribute__((ext_vector_type(4)));

// Workspace layout (float offsets) — ~1 MB total, unchanged from R4/R5.
#define C2_OFF      0
#define H2_OFF      8192
#define BESTP_OFF   16384
#define SECONDP_OFF (BESTP_OFF + 8*8192)
#define IDXP_OFF    (SECONDP_OFF + 8*8192)
#define DISTF_OFF   (IDXP_OFF + 8*8192)
#define IDXF_OFF    (DISTF_OFF + 8192)
#define GAP_OFF     (IDXF_OFF + 8192)
#define FCNT_OFF    245760
#define FLIST_OFF   245776
#define PBEST_OFF   245840
#define PIDX_OFF    (PBEST_OFF + 8192)
#define MAXSLOT     64

// Packed bf16 hi/lo arrays in the FIRST 16 MB of d_out (writeout overwrites later).
// Layout: per (panel p of 16 rows, chunk c of 32 k): 64 lanes x 16 B; lane=(kg<<4)|ln15
// holds row p*16+ln15, k=c*32+kg*8..+7. Segment address = ((p*8+c)*64+lane)*16 bytes.
#define PK_AHI ((size_t)0)
#define PK_ALO ((size_t)4 << 20)
#define PK_BHI ((size_t)8 << 20)
#define PK_BLO ((size_t)12 << 20)

// ---------------------------------------------------------------------------
__device__ __forceinline__ void async_copy16(const void* g, void* l) {
    __builtin_amdgcn_global_load_lds(
        (const __attribute__((address_space(1))) unsigned int*)g,
        (__attribute__((address_space(3))) unsigned int*)l, 16, 0, 0);
}

// fp32 -> bf16 hi/lo split, two elements at a time (RNE both; residual exact).
__device__ __forceinline__ void conv2(float a, float b, unsigned& hi, unsigned& lo) {
    float2 p0 = make_float2(a, b);
    __hip_bfloat162 hb = __float22bfloat162_rn(p0);
    unsigned h = *(unsigned*)&hb;
    hi = h;
    float ra = a - __uint_as_float(h << 16);
    float rb = b - __uint_as_float(h & 0xFFFF0000u);
    float2 p1 = make_float2(ra, rb);
    __hip_bfloat162 lb = __float22bfloat162_rn(p1);
    lo = *(unsigned*)&lb;
}

// ---------------------------------------------------------------------------
__global__ __launch_bounds__(256) void prep_sq(const float* __restrict__ h,
                                               const float* __restrict__ cb,
                                               float* __restrict__ ws) {
    if (blockIdx.x == 0 && threadIdx.x == 0) ((int*)ws)[FCNT_OFF] = 0;
    int blk  = blockIdx.x;
    int wave = threadIdx.x >> 6;
    int lane = threadIdx.x & 63;
    bool isH = blk >= 2048;
    int idx  = (isH ? (blk - 2048) : blk) * 4 + wave;
    const float* src = isH ? h : cb;
    const float4* p = (const float4*)(src + (size_t)idx * H_DIM);
    float4 v = p[lane];
    float s = v.x*v.x + v.y*v.y + v.z*v.z + v.w*v.w;
    #pragma unroll
    for (int off = 32; off > 0; off >>= 1) s += __shfl_down(s, off, 64);
    if (lane == 0) ws[(isH ? H2_OFF : C2_OFF) + idx] = s;
}

// ---------------------------------------------------------------------------
// Pack h and cb into hi/lo bf16 fragment-order arrays. One (panel,chunk) per wave.
__global__ __launch_bounds__(256) void pack_kernel(const float* __restrict__ h,
                                                   const float* __restrict__ cb,
                                                   char* __restrict__ out) {
    int w    = threadIdx.x >> 6;
    int lane = threadIdx.x & 63;
    int ln15 = lane & 15;
    int kg   = lane >> 4;
    bool isB = blockIdx.x >= 1024;
    int u = ((blockIdx.x & 1023) << 2) + w;      // 0..4095 (panel*8 + chunk)
    int p = u >> 3, c = u & 7;
    const float* src = isB ? cb : h;
    char* hiB = out + (isB ? PK_BHI : PK_AHI);
    char* loB = out + (isB ? PK_BLO : PK_ALO);
    const float* s = src + (size_t)(p * 16 + ln15) * H_DIM + c * 32 + kg * 8;
    float4 v0 = *(const float4*)s;
    float4 v1 = *(const float4*)(s + 4);
    unsigned h0, h1, h2, h3, l0, l1, l2, l3;
    conv2(v0.x, v0.y, h0, l0);
    conv2(v0.z, v0.w, h1, l1);
    conv2(v1.x, v1.y, h2, l2);
    conv2(v1.z, v1.w, h3, l3);
    size_t off = ((size_t)u * 64 + lane) * 16;
    *(uint4*)(hiB + off) = make_uint4(h0, h1, h2, h3);
    *(uint4*)(loB + off) = make_uint4(l0, l1, l2, l3);
}

// ---------------------------------------------------------------------------
// A: bf16-split MFMA GEMM-min, 64x128 per wave (4x8 tiles), 128x256 per block/ct.
// LDS 48 KB: A-hi 0 | A-lo 8K | B-hi 16K | B-lo 32K, 1 KB segments, lane*16 reads
// (conflict-free). Staging: 48 segments/kc, 12 per wave via global_load_lds(16B).
__global__ __launch_bounds__(256) void vq_min_kernel(const char* __restrict__ pk,
                                                     float* __restrict__ ws) {
    __shared__ __align__(16) char smem[49152];
    const int tid  = threadIdx.x;
    const int w    = tid >> 6;
    const int lane = tid & 63;
    const int ln15 = lane & 15;
    const int kg   = lane >> 4;
    const int wm   = (w >> 1) * 64;      // wave row offset in 128-row block
    const int wn   = (w & 1) * 128;      // wave col offset in 256-code tile
    const int am   = (w >> 1) * 4;       // local A panel base (4 panels of 16)
    const int bn   = (w & 1) * 8;        // local B panel base (8 panels of 16)

    const int rowpan0 = blockIdx.x * 8;  // global A panel base (8 panels = 128 rows)
    const float* c2g = ws + C2_OFF;

    float best16[16], sec16[16];
    int   idx16[16];
    #pragma unroll
    for (int t = 0; t < 16; t++) { best16[t] = 3.4e38f; sec16[t] = 3.4e38f; idx16[t] = 0; }

    #pragma unroll 1
    for (int ct = 0; ct < 4; ++ct) {
        const int kb      = blockIdx.y * KSPLIT + ct * 256;
        const int colpan0 = kb >> 4;     // 16 B panels of 16 codes
        f32x4 acc[4][8];
        #pragma unroll
        for (int i = 0; i < 4; i++)
            #pragma unroll
            for (int j = 0; j < 8; j++) acc[i][j] = (f32x4){0.f, 0.f, 0.f, 0.f};

        #pragma unroll 1
        for (int kc = 0; kc < 8; ++kc) {
            __syncthreads();                     // prior readers done before overwrite
            #pragma unroll
            for (int q = 0; q < 12; ++q) {
                int s = w * 12 + q;              // 0..47, wave-uniform
                const char* g;
                if (s < 16) {                    // A: 8 hi + 8 lo panels
                    int half = s >> 3, pan = s & 7;
                    g = pk + (half ? PK_ALO : PK_AHI)
                           + (((size_t)(rowpan0 + pan) * 8 + kc) * 64 + lane) * 16;
                } else {                         // B: 16 hi + 16 lo panels
                    int t2 = s - 16, half = t2 >> 4, pan = t2 & 15;
                    g = pk + (half ? PK_BLO : PK_BHI)
                           + (((size_t)(colpan0 + pan) * 8 + kc) * 64 + lane) * 16;
                }
                async_copy16(g, smem + s * 1024);
            }
            __syncthreads();                     // drains vmcnt for global_load_lds

            short8 ah[4], al[4];
            #pragma unroll
            for (int i = 0; i < 4; i++) {
                int o = (am + i) * 1024 + lane * 16;
                ah[i] = *(const short8*)(smem + o);
                al[i] = *(const short8*)(smem + 8192 + o);
            }
            #pragma unroll
            for (int j = 0; j < 8; j++) {
                int o = (bn + j) * 1024 + lane * 16;
                short8 bh = *(const short8*)(smem + 16384 + o);
                short8 bl = *(const short8*)(smem + 32768 + o);
                #pragma unroll
                for (int i = 0; i < 4; i++) {
                    acc[i][j] = __builtin_amdgcn_mfma_f32_16x16x32_bf16(ah[i], bh, acc[i][j], 0, 0, 0);
                    acc[i][j] = __builtin_amdgcn_mfma_f32_16x16x32_bf16(al[i], bh, acc[i][j], 0, 0, 0);
                    acc[i][j] = __builtin_amdgcn_mfma_f32_16x16x32_bf16(ah[i], bl, acc[i][j], 0, 0, 0);
                }
            }
        }

        // distances + tracker update (k strictly ascending within a lane: ct, then j)
        float cv[8];
        #pragma unroll
        for (int j = 0; j < 8; j++) cv[j] = c2g[kb + wn + j * 16 + ln15];
        #pragma unroll
        for (int i = 0; i < 4; i++)
            #pragma unroll
            for (int reg = 0; reg < 4; reg++) {
                const int t = i * 4 + reg;
                #pragma unroll
                for (int j = 0; j < 8; j++) {
                    float d = cv[j] - 2.f * acc[i][j][reg];
                    int   k = kb + wn + j * 16 + ln15;
                    if (d < best16[t])      { sec16[t] = best16[t]; best16[t] = d; idx16[t] = k; }
                    else if (d < sec16[t])  { sec16[t] = d; }
                }
            }
    }

    // Cross-lane merge over ln15 (butterfly within 16-lane kg group; rows uniform there).
    #pragma unroll
    for (int t = 0; t < 16; t++) {
        float b = best16[t], s2 = sec16[t];
        int   bi = idx16[t];
        #pragma unroll
        for (int m = 1; m <= 8; m <<= 1) {
            float ob = __shfl_xor(b, m, 64);
            float os = __shfl_xor(s2, m, 64);
            int   oi = __shfl_xor(bi, m, 64);
            if (ob < b)      { s2 = fminf(b, os); b = ob; bi = oi; }
            else if (ob > b) { s2 = fminf(s2, ob); }
            else             { if (oi < bi) bi = oi; s2 = b; }
        }
        best16[t] = b; sec16[t] = s2; idx16[t] = bi;
    }
    // Two column-halves per row -> small LDS merge (overlay staging; data dead).
    __syncthreads();
    float* mb = (float*)smem;
    float* ms = (float*)(smem + 1024);
    int*   mi = (int*)(smem + 2048);
    if (ln15 == 0) {
        #pragma unroll
        for (int i = 0; i < 4; i++)
            #pragma unroll
            for (int reg = 0; reg < 4; reg++) {
                int r = wm + i * 16 + kg * 4 + reg;
                int half = (w & 1);
                mb[r * 2 + half] = best16[i * 4 + reg];
                ms[r * 2 + half] = sec16[i * 4 + reg];
                mi[r * 2 + half] = idx16[i * 4 + reg];
            }
    }
    __syncthreads();
    if (tid < 128) {
        float b  = mb[tid * 2],     s2 = ms[tid * 2];
        int   bi = mi[tid * 2];
        float ob = mb[tid * 2 + 1], os = ms[tid * 2 + 1];
        int   oi = mi[tid * 2 + 1];
        if (ob < b)      { s2 = fminf(b, os); b = ob; bi = oi; }
        else if (ob > b) { s2 = fminf(s2, ob); }
        else             { if (oi < bi) bi = oi; s2 = b; }
        int row = blockIdx.x * 128 + tid;
        int s   = blockIdx.y;
        ws[BESTP_OFF   + s * N_ROWS + row] = b;
        ws[SECONDP_OFF + s * N_ROWS + row] = s2;
        ((int*)ws)[IDXP_OFF + s * N_ROWS + row] = bi;
    }
}

// ---------------------------------------------------------------------------
__global__ __launch_bounds__(256) void merge_kernel(float* __restrict__ ws) {
    int row = blockIdx.x * blockDim.x + threadIdx.x;
    if (row >= N_ROWS) return;
    float b  = ws[BESTP_OFF + row];
    float s2 = ws[SECONDP_OFF + row];
    int   bi = ((int*)ws)[IDXP_OFF + row];
    for (int s = 1; s < NSPLIT; s++) {
        float ob = ws[BESTP_OFF   + s * N_ROWS + row];
        float os = ws[SECONDP_OFF + s * N_ROWS + row];
        int   oi = ((int*)ws)[IDXP_OFF + s * N_ROWS + row];
        if (ob < b)      { s2 = fminf(b, os); b = ob; bi = oi; }
        else if (ob > b) { s2 = fminf(s2, ob); }
        else             { if (oi < bi) bi = oi; s2 = b; }
    }
    float h2 = ws[H2_OFF + row];
    ws[DISTF_OFF + row] = h2 + b;
    ((int*)ws)[IDXF_OFF + row] = bi;
    if (s2 - b <= MARGIN) {
        int slot = atomicAdd(&((int*)ws)[FCNT_OFF], 1);
        if (slot < MAXSLOT) ((int*)ws)[FLIST_OFF + slot] = row;
    }
}

// ---------------------------------------------------------------------------
__global__ __launch_bounds__(256) void fixup_part(const float* __restrict__ h,
                                                  const float* __restrict__ cb,
                                                  float* __restrict__ ws) {
    int slot = blockIdx.y;
    int n = ((const int*)ws)[FCNT_OFF];
    if (n > MAXSLOT) n = MAXSLOT;
    if (slot >= n) return;
    int row   = ((const int*)ws)[FLIST_OFF + slot];
    int base  = blockIdx.x * 128;
    int wv    = threadIdx.x >> 6;
    int lane  = threadIdx.x & 63;
    float4 hv = *(const float4*)(h + (size_t)row * H_DIM + lane * 4);

    double best = 1e300;
    int    bi   = 1 << 30;
    for (int c = base + wv; c < base + 128; c += 4) {
        float4 cv = *(const float4*)(cb + (size_t)c * H_DIM + lane * 4);
        float dx = hv.x - cv.x, dy = hv.y - cv.y, dz = hv.z - cv.z, dw = hv.w - cv.w;
        double s = (double)dx * dx + (double)dy * dy + (double)dz * dz + (double)dw * dw;
        #pragma unroll
        for (int off = 32; off > 0; off >>= 1) s += __shfl_down(s, off, 64);
        if (lane == 0 && s < best) { best = s; bi = c; }
    }
    __shared__ double sb[4];
    __shared__ int    si[4];
    if (lane == 0) { sb[wv] = best; si[wv] = bi; }
    __syncthreads();
    if (threadIdx.x == 0) {
        double b = sb[0]; int x = si[0];
        for (int t = 1; t < 4; t++)
            if (sb[t] < b || (sb[t] == b && si[t] < x)) { b = sb[t]; x = si[t]; }
        ((double*)(ws + PBEST_OFF))[slot * 64 + blockIdx.x] = b;
        ((int*)ws)[PIDX_OFF + slot * 64 + blockIdx.x] = x;
    }
}

__global__ __launch_bounds__(64) void fixup_final(float* __restrict__ ws) {
    int slot = blockIdx.x;
    int n = ((const int*)ws)[FCNT_OFF];
    if (n > MAXSLOT) n = MAXSLOT;
    if (slot >= n) return;
    int lane = threadIdx.x;
    double b = ((const double*)(ws + PBEST_OFF))[slot * 64 + lane];
    int    x = ((const int*)ws)[PIDX_OFF + slot * 64 + lane];
    #pragma unroll
    for (int off = 32; off > 0; off >>= 1) {
        double ob = __shfl_down(b, off, 64);
        int    oi = __shfl_down(x, off, 64);
        if (ob < b || (ob == b && oi < x)) { b = ob; x = oi; }
    }
    if (lane == 0) {
        int row = ((const int*)ws)[FLIST_OFF + slot];
        ws[DISTF_OFF + row] = (float)b;
        ((int*)ws)[IDXF_OFF + row] = x;
    }
}

// ---------------------------------------------------------------------------
__global__ __launch_bounds__(256) void writeout_kernel(const float* __restrict__ ws,
                                                       float* __restrict__ out) {
    int row = blockIdx.x;
    int tid = threadIdx.x;
    int bi  = ((const int*)ws)[IDXF_OFF + row];
    float4* orow = (float4*)(out + (size_t)row * K_CODES);
    #pragma unroll
    for (int i = 0; i < 8; i++) {
        int f4 = tid + 256 * i;
        float4 v = make_float4(0.f, 0.f, 0.f, 0.f);
        if ((bi >> 2) == f4) ((float*)&v)[bi & 3] = 1.0f;
        orow[f4] = v;
    }
    if (tid == 0) {
        out[(size_t)N_ROWS * K_CODES + row] = (1.25f / 256.f) * ws[DISTF_OFF + row];
    }
}

// ---------------------------------------------------------------------------
extern "C" void kernel_launch(void* const* d_in, const int* in_sizes, int n_in,
                              void* d_out, int out_size, void* d_ws, size_t ws_size,
                              hipStream_t stream) {
    const float* h  = (const float*)d_in[0];
    const float* cb = (const float*)d_in[2];
    float* out = (float*)d_out;
    float* ws  = (float*)d_ws;

    prep_sq<<<4096, 256, 0, stream>>>(h, cb, ws);
    pack_kernel<<<2048, 256, 0, stream>>>(h, cb, (char*)d_out);
    vq_min_kernel<<<dim3(N_ROWS / 128, NSPLIT), 256, 0, stream>>>((const char*)d_out, ws);
    merge_kernel<<<N_ROWS / 256, 256, 0, stream>>>(ws);
    fixup_part<<<dim3(64, MAXSLOT), 256, 0, stream>>>(h, cb, ws);
    fixup_final<<<MAXSLOT, 64, 0, stream>>>(ws);
    writeout_kernel<<<N_ROWS, 256, 0, stream>>>(ws, out);
}

// Round 7
// 608.857 us; speedup vs baseline: 1.0066x; 1.0066x over previous
//
#include <hip/hip_runtime.h>
#include <hip/hip_bf16.h>
#include <math.h>

// Problem constants (fixed by the reference).
#define N_ROWS   8192
#define K_CODES  8192
#define H_DIM    256
#define NSPLIT   16                   // 512 codes per split-column
#define MARGIN   5e-4f                // bf16-split dot err ~2e-5; 20x safety

typedef short short8 __attribute__((ext_vector_type(8)));
typedef float f32x4  __attribute__((ext_vector_type(4)));

// Workspace layout (float offsets) — identical footprint to R4-R6 (fits ws).
#define C2_OFF      0
#define H2_OFF      8192
#define DISTF_OFF   16384
#define IDXF_OFF    (DISTF_OFF + 8192)
#define FCNT_OFF    (IDXF_OFF + 8192)
#define FLIST_OFF   (FCNT_OFF + 16)
#define PBEST_OFF   (FLIST_OFF + 64)          // double[64][64] area (8-aligned)
#define PIDX_OFF    (PBEST_OFF + 8192)
#define MAXSLOT     64

// d_out scratch map (256 MB; writeout fully overwrites at the end):
//   [0,16M):   packed bf16 hi/lo fragment arrays
//   [16M,17.5M): per-split tracker partials (16 splits x 8192 rows)
// Pack layout: per (panel p of 16 rows, chunk c of 32 k): 64 lanes x 16 B;
// lane=(kg<<4)|ln15 holds row p*16+ln15, k=c*32+kg*8..+7.
// Segment address = ((p*8+c)*64+lane)*16 bytes.
#define PK_AHI ((size_t)0)
#define PK_ALO ((size_t)4 << 20)
#define PK_BHI ((size_t)8 << 20)
#define PK_BLO ((size_t)12 << 20)
#define PART_BEST ((size_t)16 << 20)
#define PART_SEC  (PART_BEST + (size_t)(NSPLIT * N_ROWS * 4))
#define PART_IDX  (PART_SEC  + (size_t)(NSPLIT * N_ROWS * 4))

// ---------------------------------------------------------------------------
// fp32 -> bf16 hi/lo split, two elements at a time (RNE both; residual exact).
__device__ __forceinline__ void conv2(float a, float b, unsigned& hi, unsigned& lo) {
    float2 p0 = make_float2(a, b);
    __hip_bfloat162 hb = __float22bfloat162_rn(p0);
    unsigned h = *(unsigned*)&hb;
    hi = h;
    float ra = a - __uint_as_float(h << 16);
    float rb = b - __uint_as_float(h & 0xFFFF0000u);
    float2 p1 = make_float2(ra, rb);
    __hip_bfloat162 lb = __float22bfloat162_rn(p1);
    lo = *(unsigned*)&lb;
}

// ---------------------------------------------------------------------------
__global__ __launch_bounds__(256) void prep_sq(const float* __restrict__ h,
                                               const float* __restrict__ cb,
                                               float* __restrict__ ws) {
    if (blockIdx.x == 0 && threadIdx.x == 0) ((int*)ws)[FCNT_OFF] = 0;
    int blk  = blockIdx.x;
    int wave = threadIdx.x >> 6;
    int lane = threadIdx.x & 63;
    bool isH = blk >= 2048;
    int idx  = (isH ? (blk - 2048) : blk) * 4 + wave;
    const float* src = isH ? h : cb;
    const float4* p = (const float4*)(src + (size_t)idx * H_DIM);
    float4 v = p[lane];
    float s = v.x*v.x + v.y*v.y + v.z*v.z + v.w*v.w;
    #pragma unroll
    for (int off = 32; off > 0; off >>= 1) s += __shfl_down(s, off, 64);
    if (lane == 0) ws[(isH ? H2_OFF : C2_OFF) + idx] = s;
}

// ---------------------------------------------------------------------------
// Pack h and cb into hi/lo bf16 fragment-order arrays. One (panel,chunk) per wave.
__global__ __launch_bounds__(256) void pack_kernel(const float* __restrict__ h,
                                                   const float* __restrict__ cb,
                                                   char* __restrict__ out) {
    int w    = threadIdx.x >> 6;
    int lane = threadIdx.x & 63;
    int ln15 = lane & 15;
    int kg   = lane >> 4;
    bool isB = blockIdx.x >= 1024;
    int u = ((blockIdx.x & 1023) << 2) + w;      // 0..4095 (panel*8 + chunk)
    int p = u >> 3, c = u & 7;
    const float* src = isB ? cb : h;
    char* hiB = out + (isB ? PK_BHI : PK_AHI);
    char* loB = out + (isB ? PK_BLO : PK_ALO);
    const float* s = src + (size_t)(p * 16 + ln15) * H_DIM + c * 32 + kg * 8;
    float4 v0 = *(const float4*)s;
    float4 v1 = *(const float4*)(s + 4);
    unsigned h0, h1, h2, h3, l0, l1, l2, l3;
    conv2(v0.x, v0.y, h0, l0);
    conv2(v0.z, v0.w, h1, l1);
    conv2(v1.x, v1.y, h2, l2);
    conv2(v1.z, v1.w, h3, l3);
    size_t off = ((size_t)u * 64 + lane) * 16;
    *(uint4*)(hiB + off) = make_uint4(h0, h1, h2, h3);
    *(uint4*)(loB + off) = make_uint4(l0, l1, l2, l3);
}

// ---------------------------------------------------------------------------
// A: barrier-free MFMA GEMM-min. One wave = 64 rows x 512 codes; fragments
// loaded DIRECTLY from packed global arrays (coalesced dwordx4, L1/L2-cached).
// No LDS, no __syncthreads, no vmcnt(0) drain. 4 waves/block share a row-band.
__global__ __launch_bounds__(256, 1) void vq_min_kernel(const char* __restrict__ pk,
                                                        const float* __restrict__ c2g,
                                                        float* __restrict__ pbest,
                                                        float* __restrict__ psec,
                                                        int* __restrict__ pidx) {
    const int w     = threadIdx.x >> 6;
    const int lane  = threadIdx.x & 63;
    const int ln15  = lane & 15;
    const int kg    = lane >> 4;
    const int g     = blockIdx.x * 4 + w;
    const int band  = g >> 4;            // 0..127 (64-row band)
    const int split = g & 15;            // 0..15  (512-code column)
    const int lb    = lane * 16;

    // Per-wave fragment base pointers (A: 4 panels of 16 rows; B: 32 panels).
    const char* Ah = pk + PK_AHI + (size_t)band * 32768 + lb;
    const char* Al = pk + PK_ALO + (size_t)band * 32768 + lb;
    const char* Bh = pk + PK_BHI + (size_t)split * (32 * 8192) + lb;
    const char* Bl = pk + PK_BLO + (size_t)split * (32 * 8192) + lb;

    float best16[16], sec16[16];
    int   idx16[16];
    #pragma unroll
    for (int t = 0; t < 16; t++) { best16[t] = 3.4e38f; sec16[t] = 3.4e38f; idx16[t] = 0; }

    #pragma unroll 1
    for (int ct = 0; ct < 8; ++ct) {                 // 64-code tiles
        f32x4 acc[4][4];
        #pragma unroll
        for (int i = 0; i < 4; i++)
            #pragma unroll
            for (int j = 0; j < 4; j++) acc[i][j] = (f32x4){0.f, 0.f, 0.f, 0.f};

        #pragma unroll 2
        for (int kc = 0; kc < 8; ++kc) {             // 32-k chunks
            short8 ah[4], al[4], bh[4], bl[4];
            #pragma unroll
            for (int i = 0; i < 4; ++i) {
                ah[i] = *(const short8*)(Ah + i * 8192 + kc * 1024);
                al[i] = *(const short8*)(Al + i * 8192 + kc * 1024);
                bh[i] = *(const short8*)(Bh + (size_t)(ct * 4 + i) * 8192 + kc * 1024);
                bl[i] = *(const short8*)(Bl + (size_t)(ct * 4 + i) * 8192 + kc * 1024);
            }
            #pragma unroll
            for (int i = 0; i < 4; i++)
                #pragma unroll
                for (int j = 0; j < 4; j++) {
                    acc[i][j] = __builtin_amdgcn_mfma_f32_16x16x32_bf16(ah[i], bh[j], acc[i][j], 0, 0, 0);
                    acc[i][j] = __builtin_amdgcn_mfma_f32_16x16x32_bf16(al[i], bh[j], acc[i][j], 0, 0, 0);
                    acc[i][j] = __builtin_amdgcn_mfma_f32_16x16x32_bf16(ah[i], bl[j], acc[i][j], 0, 0, 0);
                }
        }

        // distances + tracker update (k ascending per lane: ct-major, j-minor)
        const int kbase = split * 512 + ct * 64;
        float cv[4];
        #pragma unroll
        for (int j = 0; j < 4; j++) cv[j] = c2g[kbase + j * 16 + ln15];
        #pragma unroll
        for (int i = 0; i < 4; i++)
            #pragma unroll
            for (int reg = 0; reg < 4; reg++) {
                const int t = i * 4 + reg;
                #pragma unroll
                for (int j = 0; j < 4; j++) {
                    float d = cv[j] - 2.f * acc[i][j][reg];
                    int   k = kbase + j * 16 + ln15;
                    if (d < best16[t])      { sec16[t] = best16[t]; best16[t] = d; idx16[t] = k; }
                    else if (d < sec16[t])  { sec16[t] = d; }
                }
            }
    }

    // Cross-lane merge over ln15 (butterfly; rows uniform within kg group).
    #pragma unroll
    for (int t = 0; t < 16; t++) {
        float b = best16[t], s2 = sec16[t];
        int   bi = idx16[t];
        #pragma unroll
        for (int m = 1; m <= 8; m <<= 1) {
            float ob = __shfl_xor(b, m, 64);
            float os = __shfl_xor(s2, m, 64);
            int   oi = __shfl_xor(bi, m, 64);
            if (ob < b)      { s2 = fminf(b, os); b = ob; bi = oi; }
            else if (ob > b) { s2 = fminf(s2, ob); }
            else             { if (oi < bi) bi = oi; s2 = b; }
        }
        best16[t] = b; sec16[t] = s2; idx16[t] = bi;
    }
    if (ln15 == 0) {                         // lanes 0,16,32,48 hold merged rows
        #pragma unroll
        for (int t = 0; t < 16; t++) {
            int i = t >> 2, reg = t & 3;
            int row = band * 64 + i * 16 + kg * 4 + reg;
            pbest[split * N_ROWS + row] = best16[t];
            psec [split * N_ROWS + row] = sec16[t];
            pidx [split * N_ROWS + row] = idx16[t];
        }
    }
}

// ---------------------------------------------------------------------------
// M: merge 16 split-columns per row; finals to ws; flag near-ties.
__global__ __launch_bounds__(256) void merge_kernel(const float* __restrict__ pbest,
                                                    const float* __restrict__ psec,
                                                    const int* __restrict__ pidx,
                                                    float* __restrict__ ws) {
    int row = blockIdx.x * blockDim.x + threadIdx.x;
    if (row >= N_ROWS) return;
    float b  = pbest[row];
    float s2 = psec[row];
    int   bi = pidx[row];
    for (int s = 1; s < NSPLIT; s++) {
        float ob = pbest[s * N_ROWS + row];
        float os = psec [s * N_ROWS + row];
        int   oi = pidx [s * N_ROWS + row];
        if (ob < b)      { s2 = fminf(b, os); b = ob; bi = oi; }
        else if (ob > b) { s2 = fminf(s2, ob); }
        else             { if (oi < bi) bi = oi; s2 = b; }
    }
    float h2 = ws[H2_OFF + row];
    ws[DISTF_OFF + row] = h2 + b;
    ((int*)ws)[IDXF_OFF + row] = bi;
    if (s2 - b <= MARGIN) {
        int slot = atomicAdd(&((int*)ws)[FCNT_OFF], 1);
        if (slot < MAXSLOT) ((int*)ws)[FLIST_OFF + slot] = row;
    }
}

// ---------------------------------------------------------------------------
__global__ __launch_bounds__(256) void fixup_part(const float* __restrict__ h,
                                                  const float* __restrict__ cb,
                                                  float* __restrict__ ws) {
    int slot = blockIdx.y;
    int n = ((const int*)ws)[FCNT_OFF];
    if (n > MAXSLOT) n = MAXSLOT;
    if (slot >= n) return;
    int row   = ((const int*)ws)[FLIST_OFF + slot];
    int base  = blockIdx.x * 128;
    int wv    = threadIdx.x >> 6;
    int lane  = threadIdx.x & 63;
    float4 hv = *(const float4*)(h + (size_t)row * H_DIM + lane * 4);

    double best = 1e300;
    int    bi   = 1 << 30;
    for (int c = base + wv; c < base + 128; c += 4) {
        float4 cv = *(const float4*)(cb + (size_t)c * H_DIM + lane * 4);
        float dx = hv.x - cv.x, dy = hv.y - cv.y, dz = hv.z - cv.z, dw = hv.w - cv.w;
        double s = (double)dx * dx + (double)dy * dy + (double)dz * dz + (double)dw * dw;
        #pragma unroll
        for (int off = 32; off > 0; off >>= 1) s += __shfl_down(s, off, 64);
        if (lane == 0 && s < best) { best = s; bi = c; }
    }
    __shared__ double sb[4];
    __shared__ int    si[4];
    if (lane == 0) { sb[wv] = best; si[wv] = bi; }
    __syncthreads();
    if (threadIdx.x == 0) {
        double b = sb[0]; int x = si[0];
        for (int t = 1; t < 4; t++)
            if (sb[t] < b || (sb[t] == b && si[t] < x)) { b = sb[t]; x = si[t]; }
        ((double*)(ws + PBEST_OFF))[slot * 64 + blockIdx.x] = b;
        ((int*)ws)[PIDX_OFF + slot * 64 + blockIdx.x] = x;
    }
}

__global__ __launch_bounds__(64) void fixup_final(float* __restrict__ ws) {
    int slot = blockIdx.x;
    int n = ((const int*)ws)[FCNT_OFF];
    if (n > MAXSLOT) n = MAXSLOT;
    if (slot >= n) return;
    int lane = threadIdx.x;
    double b = ((const double*)(ws + PBEST_OFF))[slot * 64 + lane];
    int    x = ((const int*)ws)[PIDX_OFF + slot * 64 + lane];
    #pragma unroll
    for (int off = 32; off > 0; off >>= 1) {
        double ob = __shfl_down(b, off, 64);
        int    oi = __shfl_down(x, off, 64);
        if (ob < b || (ob == b && oi < x)) { b = ob; x = oi; }
    }
    if (lane == 0) {
        int row = ((const int*)ws)[FLIST_OFF + slot];
        ws[DISTF_OFF + row] = (float)b;
        ((int*)ws)[IDXF_OFF + row] = x;
    }
}

// ---------------------------------------------------------------------------
__global__ __launch_bounds__(256) void writeout_kernel(const float* __restrict__ ws,
                                                       float* __restrict__ out) {
    int row = blockIdx.x;
    int tid = threadIdx.x;
    int bi  = ((const int*)ws)[IDXF_OFF + row];
    float4* orow = (float4*)(out + (size_t)row * K_CODES);
    #pragma unroll
    for (int i = 0; i < 8; i++) {
        int f4 = tid + 256 * i;
        float4 v = make_float4(0.f, 0.f, 0.f, 0.f);
        if ((bi >> 2) == f4) ((float*)&v)[bi & 3] = 1.0f;
        orow[f4] = v;
    }
    if (tid == 0) {
        out[(size_t)N_ROWS * K_CODES + row] = (1.25f / 256.f) * ws[DISTF_OFF + row];
    }
}

// ---------------------------------------------------------------------------
extern "C" void kernel_launch(void* const* d_in, const int* in_sizes, int n_in,
                              void* d_out, int out_size, void* d_ws, size_t ws_size,
                              hipStream_t stream) {
    const float* h  = (const float*)d_in[0];
    const float* cb = (const float*)d_in[2];
    float* out = (float*)d_out;
    float* ws  = (float*)d_ws;
    char*  pk  = (char*)d_out;

    float* pbest = (float*)(pk + PART_BEST);
    float* psec  = (float*)(pk + PART_SEC);
    int*   pidx  = (int*)(pk + PART_IDX);

    prep_sq<<<4096, 256, 0, stream>>>(h, cb, ws);
    pack_kernel<<<2048, 256, 0, stream>>>(h, cb, pk);
    vq_min_kernel<<<512, 256, 0, stream>>>(pk, ws, pbest, psec, pidx);
    merge_kernel<<<N_ROWS / 256, 256, 0, stream>>>(pbest, psec, pidx, ws);
    fixup_part<<<dim3(64, MAXSLOT), 256, 0, stream>>>(h, cb, ws);
    fixup_final<<<MAXSLOT, 64, 0, stream>>>(ws);
    writeout_kernel<<<N_ROWS, 256, 0, stream>>>(ws, out);
}

// Round 8
// 434.289 us; speedup vs baseline: 1.4113x; 1.4020x over previous
//
#include <hip/hip_runtime.h>
#include <hip/hip_bf16.h>
#include <math.h>

// Problem constants (fixed by the reference).
#define N_ROWS   8192
#define K_CODES  8192
#define H_DIM    256
#define NSPLIT   16                   // 512 codes per split-column (R8: was 8 — occupancy fix)
#define KSPLIT   (K_CODES / NSPLIT)   // 512 codes -> 4 ct tiles of 128
#define MARGIN   5e-4f                // bf16 hi/lo dot err ~2e-5; 20x safety

typedef short short8 __attribute__((ext_vector_type(8)));
typedef float f32x4  __attribute__((ext_vector_type(4)));

// Workspace layout (float offsets).
#define C2_OFF      0
#define H2_OFF      8192
#define DISTF_OFF   16384
#define IDXF_OFF    (DISTF_OFF + 8192)
#define FCNT_OFF    (IDXF_OFF + 8192)
#define FLIST_OFF   (FCNT_OFF + 16)
#define PBEST_OFF   (FLIST_OFF + 64)          // double[64][64] area (8-aligned)
#define PIDX_OFF    (PBEST_OFF + 8192)
#define MAXSLOT     64

// d_out scratch map (writeout fully overwrites d_out at the end):
//   [0,16M): packed bf16 hi/lo fragment arrays
//   [16M,+): per-split tracker partials (16 splits x 8192 rows)
// Pack layout: per (panel p of 16 rows, chunk c of 32 k): 64 lanes x 16 B;
// lane=(kg<<4)|ln15 holds row p*16+ln15, k=c*32+kg*8..+7.
// Segment address = ((p*8+c)*64+lane)*16 bytes.
#define PK_AHI ((size_t)0)
#define PK_ALO ((size_t)4 << 20)
#define PK_BHI ((size_t)8 << 20)
#define PK_BLO ((size_t)12 << 20)
#define PART_BEST ((size_t)16 << 20)
#define PART_SEC  (PART_BEST + (size_t)(NSPLIT * N_ROWS * 4))
#define PART_IDX  (PART_SEC  + (size_t)(NSPLIT * N_ROWS * 4))

// ---------------------------------------------------------------------------
__device__ __forceinline__ void async_copy16(const void* g, void* l) {
    __builtin_amdgcn_global_load_lds(
        (const __attribute__((address_space(1))) unsigned int*)g,
        (__attribute__((address_space(3))) unsigned int*)l, 16, 0, 0);
}

// fp32 -> bf16 hi/lo split, two elements at a time (RNE both; residual exact).
__device__ __forceinline__ void conv2(float a, float b, unsigned& hi, unsigned& lo) {
    float2 p0 = make_float2(a, b);
    __hip_bfloat162 hb = __float22bfloat162_rn(p0);
    unsigned h = *(unsigned*)&hb;
    hi = h;
    float ra = a - __uint_as_float(h << 16);
    float rb = b - __uint_as_float(h & 0xFFFF0000u);
    float2 p1 = make_float2(ra, rb);
    __hip_bfloat162 lb = __float22bfloat162_rn(p1);
    lo = *(unsigned*)&lb;
}

// ---------------------------------------------------------------------------
__global__ __launch_bounds__(256) void prep_sq(const float* __restrict__ h,
                                               const float* __restrict__ cb,
                                               float* __restrict__ ws) {
    if (blockIdx.x == 0 && threadIdx.x == 0) ((int*)ws)[FCNT_OFF] = 0;
    int blk  = blockIdx.x;
    int wave = threadIdx.x >> 6;
    int lane = threadIdx.x & 63;
    bool isH = blk >= 2048;
    int idx  = (isH ? (blk - 2048) : blk) * 4 + wave;
    const float* src = isH ? h : cb;
    const float4* p = (const float4*)(src + (size_t)idx * H_DIM);
    float4 v = p[lane];
    float s = v.x*v.x + v.y*v.y + v.z*v.z + v.w*v.w;
    #pragma unroll
    for (int off = 32; off > 0; off >>= 1) s += __shfl_down(s, off, 64);
    if (lane == 0) ws[(isH ? H2_OFF : C2_OFF) + idx] = s;
}

// ---------------------------------------------------------------------------
// Pack h and cb into hi/lo bf16 fragment-order arrays. One (panel,chunk) per wave.
__global__ __launch_bounds__(256) void pack_kernel(const float* __restrict__ h,
                                                   const float* __restrict__ cb,
                                                   char* __restrict__ out) {
    int w    = threadIdx.x >> 6;
    int lane = threadIdx.x & 63;
    int ln15 = lane & 15;
    int kg   = lane >> 4;
    bool isB = blockIdx.x >= 1024;
    int u = ((blockIdx.x & 1023) << 2) + w;      // 0..4095 (panel*8 + chunk)
    int p = u >> 3, c = u & 7;
    const float* src = isB ? cb : h;
    char* hiB = out + (isB ? PK_BHI : PK_AHI);
    char* loB = out + (isB ? PK_BLO : PK_ALO);
    const float* s = src + (size_t)(p * 16 + ln15) * H_DIM + c * 32 + kg * 8;
    float4 v0 = *(const float4*)s;
    float4 v1 = *(const float4*)(s + 4);
    unsigned h0, h1, h2, h3, l0, l1, l2, l3;
    conv2(v0.x, v0.y, h0, l0);
    conv2(v0.z, v0.w, h1, l1);
    conv2(v1.x, v1.y, h2, l2);
    conv2(v1.z, v1.w, h3, l3);
    size_t off = ((size_t)u * 64 + lane) * 16;
    *(uint4*)(hiB + off) = make_uint4(h0, h1, h2, h3);
    *(uint4*)(loB + off) = make_uint4(l0, l1, l2, l3);
}

// ---------------------------------------------------------------------------
// A: bf16-split MFMA GEMM-min (R5 structure, measured-best). 4 waves of 64x64;
// block = 128 rows x 128 codes per ct, ct-loop x4 over the 512-code split.
// LDS 35 KB staging (1 KB segments, lane*16 reads: conflict-free) + merge.
// Grid 1024 blocks -> 4 blocks/CU (VGPR<=128, LDS 35.8K) = 16 waves/CU.
__global__ __launch_bounds__(256, 4) void vq_min_kernel(const char* __restrict__ pk,
                                                        const float* __restrict__ c2g,
                                                        float* __restrict__ pbest,
                                                        float* __restrict__ psec,
                                                        int* __restrict__ pidx) {
    __shared__ __align__(16) char smem[35840];
    const int tid  = threadIdx.x;
    const int w    = tid >> 6;
    const int lane = tid & 63;
    const int ln15 = lane & 15;
    const int kg   = lane >> 4;
    const int wm   = (w >> 1) * 64;      // wave row offset
    const int wn   = (w & 1) * 64;       // wave col offset
    const int am   = (w >> 1) * 4;       // local A panel base
    const int bn4  = (w & 1) * 4;        // local B panel base

    const int rowpan0 = blockIdx.x * 8;       // 8 panels = 128 rows
    const int bpan0   = blockIdx.y * (KSPLIT / 16);

    const size_t pkoff = (w == 0) ? PK_AHI : (w == 1) ? PK_ALO : (w == 2) ? PK_BHI : PK_BLO;
    char* lwave = smem + w * 8192;

    float best16[16], sec16[16];
    int   idx16[16];
    #pragma unroll
    for (int t = 0; t < 16; t++) { best16[t] = 3.4e38f; sec16[t] = 3.4e38f; idx16[t] = 0; }

    #pragma unroll 1
    for (int ct = 0; ct < KSPLIT / 128; ++ct) {
        const int kb   = blockIdx.y * KSPLIT + ct * 128;
        const int pan0 = (w < 2) ? rowpan0 : (bpan0 + ct * 8);
        f32x4 acc[4][4];
        #pragma unroll
        for (int i = 0; i < 4; i++)
            #pragma unroll
            for (int j = 0; j < 4; j++) acc[i][j] = (f32x4){0.f, 0.f, 0.f, 0.f};

        #pragma unroll 1
        for (int kc = 0; kc < 8; ++kc) {
            __syncthreads();                     // prior readers done before overwrite
            #pragma unroll
            for (int q = 0; q < 8; ++q) {
                const char* g = pk + pkoff + (((size_t)(pan0 + q) * 8 + kc) * 64 + lane) * 16;
                async_copy16(g, lwave + q * 1024);
            }
            __syncthreads();                     // drains vmcnt for global_load_lds

            short8 ah[4], al[4], bh[4], bl[4];
            #pragma unroll
            for (int i = 0; i < 4; i++) {
                int o = ((am + i) * 64 + lane) * 16;
                ah[i] = *(const short8*)(smem + o);
                al[i] = *(const short8*)(smem + 8192 + o);
            }
            #pragma unroll
            for (int j = 0; j < 4; j++) {
                int o = ((bn4 + j) * 64 + lane) * 16;
                bh[j] = *(const short8*)(smem + 16384 + o);
                bl[j] = *(const short8*)(smem + 24576 + o);
            }
            #pragma unroll
            for (int i = 0; i < 4; i++)
                #pragma unroll
                for (int j = 0; j < 4; j++) {
                    acc[i][j] = __builtin_amdgcn_mfma_f32_16x16x32_bf16(ah[i], bh[j], acc[i][j], 0, 0, 0);
                    acc[i][j] = __builtin_amdgcn_mfma_f32_16x16x32_bf16(al[i], bh[j], acc[i][j], 0, 0, 0);
                    acc[i][j] = __builtin_amdgcn_mfma_f32_16x16x32_bf16(ah[i], bl[j], acc[i][j], 0, 0, 0);
                }
        }

        // distances + tracker update (k strictly ascending within a lane)
        float cv[4];
        #pragma unroll
        for (int j = 0; j < 4; j++) cv[j] = c2g[kb + wn + j * 16 + ln15];
        #pragma unroll
        for (int i = 0; i < 4; i++)
            #pragma unroll
            for (int reg = 0; reg < 4; reg++) {
                const int t = i * 4 + reg;
                #pragma unroll
                for (int j = 0; j < 4; j++) {
                    float d = cv[j] - 2.f * acc[i][j][reg];
                    int   k = kb + wn + j * 16 + ln15;
                    if (d < best16[t])      { sec16[t] = best16[t]; best16[t] = d; idx16[t] = k; }
                    else if (d < sec16[t])  { sec16[t] = d; }
                }
            }
    }

    // Cross-lane merge over ln15 (butterfly within 16-lane kg group).
    #pragma unroll
    for (int t = 0; t < 16; t++) {
        float b = best16[t], s2 = sec16[t];
        int   bi = idx16[t];
        #pragma unroll
        for (int m = 1; m <= 8; m <<= 1) {
            float ob = __shfl_xor(b, m, 64);
            float os = __shfl_xor(s2, m, 64);
            int   oi = __shfl_xor(bi, m, 64);
            if (ob < b)      { s2 = fminf(b, os); b = ob; bi = oi; }
            else if (ob > b) { s2 = fminf(s2, ob); }
            else             { if (oi < bi) bi = oi; s2 = b; }
        }
        best16[t] = b; sec16[t] = s2; idx16[t] = bi;
    }
    // Two column-halves per row -> small LDS merge region (above staging).
    float* mb = (float*)(smem + 32768);
    float* ms = (float*)(smem + 32768 + 1024);
    int*   mi = (int*)(smem + 32768 + 2048);
    if (ln15 == 0) {
        #pragma unroll
        for (int i = 0; i < 4; i++)
            #pragma unroll
            for (int reg = 0; reg < 4; reg++) {
                int r = wm + i * 16 + kg * 4 + reg;
                int half = (w & 1);
                mb[r * 2 + half] = best16[i * 4 + reg];
                ms[r * 2 + half] = sec16[i * 4 + reg];
                mi[r * 2 + half] = idx16[i * 4 + reg];
            }
    }
    __syncthreads();
    if (tid < 128) {
        float b  = mb[tid * 2],     s2 = ms[tid * 2];
        int   bi = mi[tid * 2];
        float ob = mb[tid * 2 + 1], os = ms[tid * 2 + 1];
        int   oi = mi[tid * 2 + 1];
        if (ob < b)      { s2 = fminf(b, os); b = ob; bi = oi; }
        else if (ob > b) { s2 = fminf(s2, ob); }
        else             { if (oi < bi) bi = oi; s2 = b; }
        int row = blockIdx.x * 128 + tid;
        int s   = blockIdx.y;
        pbest[s * N_ROWS + row] = b;
        psec [s * N_ROWS + row] = s2;
        pidx [s * N_ROWS + row] = bi;
    }
}

// ---------------------------------------------------------------------------
// M: merge 16 split-columns per row; finals to ws; flag near-ties.
__global__ __launch_bounds__(256) void merge_kernel(const float* __restrict__ pbest,
                                                    const float* __restrict__ psec,
                                                    const int* __restrict__ pidx,
                                                    float* __restrict__ ws) {
    int row = blockIdx.x * blockDim.x + threadIdx.x;
    if (row >= N_ROWS) return;
    float b  = pbest[row];
    float s2 = psec[row];
    int   bi = pidx[row];
    for (int s = 1; s < NSPLIT; s++) {
        float ob = pbest[s * N_ROWS + row];
        float os = psec [s * N_ROWS + row];
        int   oi = pidx [s * N_ROWS + row];
        if (ob < b)      { s2 = fminf(b, os); b = ob; bi = oi; }
        else if (ob > b) { s2 = fminf(s2, ob); }
        else             { if (oi < bi) bi = oi; s2 = b; }
    }
    float h2 = ws[H2_OFF + row];
    ws[DISTF_OFF + row] = h2 + b;
    ((int*)ws)[IDXF_OFF + row] = bi;
    if (s2 - b <= MARGIN) {
        int slot = atomicAdd(&((int*)ws)[FCNT_OFF], 1);
        if (slot < MAXSLOT) ((int*)ws)[FLIST_OFF + slot] = row;
    }
}

// ---------------------------------------------------------------------------
__global__ __launch_bounds__(256) void fixup_part(const float* __restrict__ h,
                                                  const float* __restrict__ cb,
                                                  float* __restrict__ ws) {
    int slot = blockIdx.y;
    int n = ((const int*)ws)[FCNT_OFF];
    if (n > MAXSLOT) n = MAXSLOT;
    if (slot >= n) return;
    int row   = ((const int*)ws)[FLIST_OFF + slot];
    int base  = blockIdx.x * 128;
    int wv    = threadIdx.x >> 6;
    int lane  = threadIdx.x & 63;
    float4 hv = *(const float4*)(h + (size_t)row * H_DIM + lane * 4);

    double best = 1e300;
    int    bi   = 1 << 30;
    for (int c = base + wv; c < base + 128; c += 4) {
        float4 cv = *(const float4*)(cb + (size_t)c * H_DIM + lane * 4);
        float dx = hv.x - cv.x, dy = hv.y - cv.y, dz = hv.z - cv.z, dw = hv.w - cv.w;
        double s = (double)dx * dx + (double)dy * dy + (double)dz * dz + (double)dw * dw;
        #pragma unroll
        for (int off = 32; off > 0; off >>= 1) s += __shfl_down(s, off, 64);
        if (lane == 0 && s < best) { best = s; bi = c; }
    }
    __shared__ double sb[4];
    __shared__ int    si[4];
    if (lane == 0) { sb[wv] = best; si[wv] = bi; }
    __syncthreads();
    if (threadIdx.x == 0) {
        double b = sb[0]; int x = si[0];
        for (int t = 1; t < 4; t++)
            if (sb[t] < b || (sb[t] == b && si[t] < x)) { b = sb[t]; x = si[t]; }
        ((double*)(ws + PBEST_OFF))[slot * 64 + blockIdx.x] = b;
        ((int*)ws)[PIDX_OFF + slot * 64 + blockIdx.x] = x;
    }
}

__global__ __launch_bounds__(64) void fixup_final(float* __restrict__ ws) {
    int slot = blockIdx.x;
    int n = ((const int*)ws)[FCNT_OFF];
    if (n > MAXSLOT) n = MAXSLOT;
    if (slot >= n) return;
    int lane = threadIdx.x;
    double b = ((const double*)(ws + PBEST_OFF))[slot * 64 + lane];
    int    x = ((const int*)ws)[PIDX_OFF + slot * 64 + lane];
    #pragma unroll
    for (int off = 32; off > 0; off >>= 1) {
        double ob = __shfl_down(b, off, 64);
        int    oi = __shfl_down(x, off, 64);
        if (ob < b || (ob == b && oi < x)) { b = ob; x = oi; }
    }
    if (lane == 0) {
        int row = ((const int*)ws)[FLIST_OFF + slot];
        ws[DISTF_OFF + row] = (float)b;
        ((int*)ws)[IDXF_OFF + row] = x;
    }
}

// ---------------------------------------------------------------------------
__global__ __launch_bounds__(256) void writeout_kernel(const float* __restrict__ ws,
                                                       float* __restrict__ out) {
    int row = blockIdx.x;
    int tid = threadIdx.x;
    int bi  = ((const int*)ws)[IDXF_OFF + row];
    float4* orow = (float4*)(out + (size_t)row * K_CODES);
    #pragma unroll
    for (int i = 0; i < 8; i++) {
        int f4 = tid + 256 * i;
        float4 v = make_float4(0.f, 0.f, 0.f, 0.f);
        if ((bi >> 2) == f4) ((float*)&v)[bi & 3] = 1.0f;
        orow[f4] = v;
    }
    if (tid == 0) {
        out[(size_t)N_ROWS * K_CODES + row] = (1.25f / 256.f) * ws[DISTF_OFF + row];
    }
}

// ---------------------------------------------------------------------------
extern "C" void kernel_launch(void* const* d_in, const int* in_sizes, int n_in,
                              void* d_out, int out_size, void* d_ws, size_t ws_size,
                              hipStream_t stream) {
    const float* h  = (const float*)d_in[0];
    const float* cb = (const float*)d_in[2];
    float* out = (float*)d_out;
    float* ws  = (float*)d_ws;
    char*  pk  = (char*)d_out;

    float* pbest = (float*)(pk + PART_BEST);
    float* psec  = (float*)(pk + PART_SEC);
    int*   pidx  = (int*)(pk + PART_IDX);

    prep_sq<<<4096, 256, 0, stream>>>(h, cb, ws);
    pack_kernel<<<2048, 256, 0, stream>>>(h, cb, pk);
    vq_min_kernel<<<dim3(N_ROWS / 128, NSPLIT), 256, 0, stream>>>(pk, ws, pbest, psec, pidx);
    merge_kernel<<<N_ROWS / 256, 256, 0, stream>>>(pbest, psec, pidx, ws);
    fixup_part<<<dim3(64, MAXSLOT), 256, 0, stream>>>(h, cb, ws);
    fixup_final<<<MAXSLOT, 64, 0, stream>>>(ws);
    writeout_kernel<<<N_ROWS, 256, 0, stream>>>(ws, out);
}

// Round 11
// 425.755 us; speedup vs baseline: 1.4395x; 1.0200x over previous
//
#include <hip/hip_runtime.h>
#include <hip/hip_bf16.h>
#include <math.h>

// Problem constants (fixed by the reference).
#define N_ROWS   8192
#define K_CODES  8192
#define H_DIM    256
#define NSPLIT   16                   // 512 codes per split-column
#define KSPLIT   (K_CODES / NSPLIT)
// 3-term decomposition (ah·bh + al·bh + ah·bl): dot err ~2e-5; MARGIN 25x that.
// R10 lesson: 2-term needs MARGIN 4e-2 -> ~270 flagged rows -> fixup costs more
// than the dropped MFMA saves. 3-term + 5e-4 gives ~3-40 flagged (proven R4-R8).
#define MARGIN   5e-4f

typedef short short8 __attribute__((ext_vector_type(8)));
typedef float f32x4  __attribute__((ext_vector_type(4)));

// Workspace layout (float offsets).
#define C2_OFF      0
#define H2_OFF      8192
#define DISTF_OFF   16384
#define IDXF_OFF    (DISTF_OFF + 8192)
#define FCNT_OFF    (IDXF_OFF + 8192)
#define FLIST_OFF   (FCNT_OFF + 16)           // int[256]
#define MAXSLOT     256

// d_out scratch map (memset+scatter rebuild d_out at the end):
//   [0,16M): packed bf16 hi/lo fragment arrays
//   [16M,+): per-split tracker partials, then fixup partials
// Pack layout: per (panel p of 16 rows, chunk c of 32 k): 64 lanes x 16 B;
// lane=(kg<<4)|ln15 holds row p*16+ln15, k=c*32+kg*8..+7.
// Segment address = ((p*8+c)*64+lane)*16 bytes.
#define PK_AHI ((size_t)0)
#define PK_ALO ((size_t)4 << 20)
#define PK_BHI ((size_t)8 << 20)
#define PK_BLO ((size_t)12 << 20)
#define PART_BEST ((size_t)16 << 20)
#define PART_SEC  (PART_BEST + (size_t)(NSPLIT * N_ROWS * 4))
#define PART_IDX  (PART_SEC  + (size_t)(NSPLIT * N_ROWS * 4))
#define FIXP_BEST (PART_IDX  + (size_t)(NSPLIT * N_ROWS * 4))   // double[256][64]
#define FIXP_IDX  (FIXP_BEST + (size_t)(MAXSLOT * 64 * 8))      // int[256][64]

// ---------------------------------------------------------------------------
__device__ __forceinline__ void async_copy16(const void* g, void* l) {
    __builtin_amdgcn_global_load_lds(
        (const __attribute__((address_space(1))) unsigned int*)g,
        (__attribute__((address_space(3))) unsigned int*)l, 16, 0, 0);
}

// fp32 -> bf16 hi/lo split, two elements at a time (RNE both; residual ~exact).
__device__ __forceinline__ void conv2(float a, float b, unsigned& hi, unsigned& lo) {
    float2 p0 = make_float2(a, b);
    __hip_bfloat162 hb = __float22bfloat162_rn(p0);
    unsigned h = *(unsigned*)&hb;
    hi = h;
    float ra = a - __uint_as_float(h << 16);
    float rb = b - __uint_as_float(h & 0xFFFF0000u);
    float2 p1 = make_float2(ra, rb);
    __hip_bfloat162 lb = __float22bfloat162_rn(p1);
    lo = *(unsigned*)&lb;
}

// ---------------------------------------------------------------------------
__global__ __launch_bounds__(256) void prep_sq(const float* __restrict__ h,
                                               const float* __restrict__ cb,
                                               float* __restrict__ ws) {
    if (blockIdx.x == 0 && threadIdx.x == 0) ((int*)ws)[FCNT_OFF] = 0;
    int blk  = blockIdx.x;
    int wave = threadIdx.x >> 6;
    int lane = threadIdx.x & 63;
    bool isH = blk >= 2048;
    int idx  = (isH ? (blk - 2048) : blk) * 4 + wave;
    const float* src = isH ? h : cb;
    const float4* p = (const float4*)(src + (size_t)idx * H_DIM);
    float4 v = p[lane];
    float s = v.x*v.x + v.y*v.y + v.z*v.z + v.w*v.w;
    #pragma unroll
    for (int off = 32; off > 0; off >>= 1) s += __shfl_down(s, off, 64);
    if (lane == 0) ws[(isH ? H2_OFF : C2_OFF) + idx] = s;
}

// ---------------------------------------------------------------------------
// Pack h and cb into hi/lo bf16 fragment-order arrays. One (panel,chunk) per wave.
__global__ __launch_bounds__(256) void pack_kernel(const float* __restrict__ h,
                                                   const float* __restrict__ cb,
                                                   char* __restrict__ out) {
    int w    = threadIdx.x >> 6;
    int lane = threadIdx.x & 63;
    int ln15 = lane & 15;
    int kg   = lane >> 4;
    bool isB = blockIdx.x >= 1024;
    int u = ((blockIdx.x & 1023) << 2) + w;      // 0..4095 (panel*8 + chunk)
    int p = u >> 3, c = u & 7;
    const float* src = isB ? cb : h;
    char* hiB = out + (isB ? PK_BHI : PK_AHI);
    char* loB = out + (isB ? PK_BLO : PK_ALO);
    const float* s = src + (size_t)(p * 16 + ln15) * H_DIM + c * 32 + kg * 8;
    float4 v0 = *(const float4*)s;
    float4 v1 = *(const float4*)(s + 4);
    unsigned h0, h1, h2, h3, l0, l1, l2, l3;
    conv2(v0.x, v0.y, h0, l0);
    conv2(v0.z, v0.w, h1, l1);
    conv2(v1.x, v1.y, h2, l2);
    conv2(v1.z, v1.w, h3, l3);
    size_t off = ((size_t)u * 64 + lane) * 16;
    *(uint4*)(hiB + off) = make_uint4(h0, h1, h2, h3);
    *(uint4*)(loB + off) = make_uint4(l0, l1, l2, l3);
}

// ---------------------------------------------------------------------------
// A: 3-term MFMA GEMM-min (R8 structure, measured-best & correctness-proven).
// 4 waves of 64x64; block = 128 rows x 128 codes per ct, ct x4 over the split.
// LDS 32K staging (1 KB segments, lane*16 reads: conflict-free) + 3K merge.
__global__ __launch_bounds__(256, 4) void vq_min_kernel(const char* __restrict__ pk,
                                                        const float* __restrict__ c2g,
                                                        float* __restrict__ pbest,
                                                        float* __restrict__ psec,
                                                        int* __restrict__ pidx) {
    __shared__ __align__(16) char smem[35840];
    const int tid  = threadIdx.x;
    const int w    = tid >> 6;
    const int lane = tid & 63;
    const int ln15 = lane & 15;
    const int kg   = lane >> 4;
    const int wm   = (w >> 1) * 64;      // wave row offset
    const int wn   = (w & 1) * 64;       // wave col offset
    const int am   = (w >> 1) * 4;       // local A panel base
    const int bn4  = (w & 1) * 4;        // local B panel base

    const int rowpan0 = blockIdx.x * 8;       // 8 panels = 128 rows
    const int bpan0   = blockIdx.y * (KSPLIT / 16);

    const size_t pkoff = (w == 0) ? PK_AHI : (w == 1) ? PK_ALO : (w == 2) ? PK_BHI : PK_BLO;
    char* lwave = smem + w * 8192;

    float best16[16], sec16[16];
    int   idx16[16];
    #pragma unroll
    for (int t = 0; t < 16; t++) { best16[t] = 3.4e38f; sec16[t] = 3.4e38f; idx16[t] = 0; }

    #pragma unroll 1
    for (int ct = 0; ct < KSPLIT / 128; ++ct) {
        const int kb   = blockIdx.y * KSPLIT + ct * 128;
        const int pan0 = (w < 2) ? rowpan0 : (bpan0 + ct * 8);
        f32x4 acc[4][4];
        #pragma unroll
        for (int i = 0; i < 4; i++)
            #pragma unroll
            for (int j = 0; j < 4; j++) acc[i][j] = (f32x4){0.f, 0.f, 0.f, 0.f};

        #pragma unroll 1
        for (int kc = 0; kc < 8; ++kc) {
            __syncthreads();                     // prior readers done before overwrite
            #pragma unroll
            for (int q = 0; q < 8; ++q) {
                const char* g = pk + pkoff + (((size_t)(pan0 + q) * 8 + kc) * 64 + lane) * 16;
                async_copy16(g, lwave + q * 1024);
            }
            __syncthreads();                     // drains vmcnt for global_load_lds

            short8 ah[4], al[4], bh[4], bl[4];
            #pragma unroll
            for (int i = 0; i < 4; i++) {
                int o = ((am + i) * 64 + lane) * 16;
                ah[i] = *(const short8*)(smem + o);
                al[i] = *(const short8*)(smem + 8192 + o);
            }
            #pragma unroll
            for (int j = 0; j < 4; j++) {
                int o = ((bn4 + j) * 64 + lane) * 16;
                bh[j] = *(const short8*)(smem + 16384 + o);
                bl[j] = *(const short8*)(smem + 24576 + o);
            }
            #pragma unroll
            for (int i = 0; i < 4; i++)
                #pragma unroll
                for (int j = 0; j < 4; j++) {
                    acc[i][j] = __builtin_amdgcn_mfma_f32_16x16x32_bf16(ah[i], bh[j], acc[i][j], 0, 0, 0);
                    acc[i][j] = __builtin_amdgcn_mfma_f32_16x16x32_bf16(al[i], bh[j], acc[i][j], 0, 0, 0);
                    acc[i][j] = __builtin_amdgcn_mfma_f32_16x16x32_bf16(ah[i], bl[j], acc[i][j], 0, 0, 0);
                }
        }

        // distances + tracker update (k strictly ascending within a lane)
        float cv[4];
        #pragma unroll
        for (int j = 0; j < 4; j++) cv[j] = c2g[kb + wn + j * 16 + ln15];
        #pragma unroll
        for (int i = 0; i < 4; i++)
            #pragma unroll
            for (int reg = 0; reg < 4; reg++) {
                const int t = i * 4 + reg;
                #pragma unroll
                for (int j = 0; j < 4; j++) {
                    float d = cv[j] - 2.f * acc[i][j][reg];
                    int   k = kb + wn + j * 16 + ln15;
                    if (d < best16[t])      { sec16[t] = best16[t]; best16[t] = d; idx16[t] = k; }
                    else if (d < sec16[t])  { sec16[t] = d; }
                }
            }
    }

    // Cross-lane merge over ln15 (butterfly within 16-lane kg group).
    #pragma unroll
    for (int t = 0; t < 16; t++) {
        float b = best16[t], s2 = sec16[t];
        int   bi = idx16[t];
        #pragma unroll
        for (int m = 1; m <= 8; m <<= 1) {
            float ob = __shfl_xor(b, m, 64);
            float os = __shfl_xor(s2, m, 64);
            int   oi = __shfl_xor(bi, m, 64);
            if (ob < b)      { s2 = fminf(b, os); b = ob; bi = oi; }
            else if (ob > b) { s2 = fminf(s2, ob); }
            else             { if (oi < bi) bi = oi; s2 = b; }
        }
        best16[t] = b; sec16[t] = s2; idx16[t] = bi;
    }
    // Two column-halves per row -> small LDS merge region (above staging).
    float* mb = (float*)(smem + 32768);
    float* ms = (float*)(smem + 32768 + 1024);
    int*   mi = (int*)(smem + 32768 + 2048);
    if (ln15 == 0) {
        #pragma unroll
        for (int i = 0; i < 4; i++)
            #pragma unroll
            for (int reg = 0; reg < 4; reg++) {
                int r = wm + i * 16 + kg * 4 + reg;
                int half = (w & 1);
                mb[r * 2 + half] = best16[i * 4 + reg];
                ms[r * 2 + half] = sec16[i * 4 + reg];
                mi[r * 2 + half] = idx16[i * 4 + reg];
            }
    }
    __syncthreads();
    if (tid < 128) {
        float b  = mb[tid * 2],     s2 = ms[tid * 2];
        int   bi = mi[tid * 2];
        float ob = mb[tid * 2 + 1], os = ms[tid * 2 + 1];
        int   oi = mi[tid * 2 + 1];
        if (ob < b)      { s2 = fminf(b, os); b = ob; bi = oi; }
        else if (ob > b) { s2 = fminf(s2, ob); }
        else             { if (oi < bi) bi = oi; s2 = b; }
        int row = blockIdx.x * 128 + tid;
        int s   = blockIdx.y;
        pbest[s * N_ROWS + row] = b;
        psec [s * N_ROWS + row] = s2;
        pidx [s * N_ROWS + row] = bi;
    }
}

// ---------------------------------------------------------------------------
__global__ __launch_bounds__(256) void merge_kernel(const float* __restrict__ pbest,
                                                    const float* __restrict__ psec,
                                                    const int* __restrict__ pidx,
                                                    float* __restrict__ ws) {
    int row = blockIdx.x * blockDim.x + threadIdx.x;
    if (row >= N_ROWS) return;
    float b  = pbest[row];
    float s2 = psec[row];
    int   bi = pidx[row];
    for (int s = 1; s < NSPLIT; s++) {
        float ob = pbest[s * N_ROWS + row];
        float os = psec [s * N_ROWS + row];
        int   oi = pidx [s * N_ROWS + row];
        if (ob < b)      { s2 = fminf(b, os); b = ob; bi = oi; }
        else if (ob > b) { s2 = fminf(s2, ob); }
        else             { if (oi < bi) bi = oi; s2 = b; }
    }
    float h2 = ws[H2_OFF + row];
    ws[DISTF_OFF + row] = h2 + b;
    ((int*)ws)[IDXF_OFF + row] = bi;
    if (s2 - b <= MARGIN) {
        int slot = atomicAdd(&((int*)ws)[FCNT_OFF], 1);
        if (slot < MAXSLOT) ((int*)ws)[FLIST_OFF + slot] = row;
    }
}

// ---------------------------------------------------------------------------
__global__ __launch_bounds__(256) void fixup_part(const float* __restrict__ h,
                                                  const float* __restrict__ cb,
                                                  float* __restrict__ ws,
                                                  double* __restrict__ fbest,
                                                  int* __restrict__ fidx) {
    int slot = blockIdx.y;
    int n = ((const int*)ws)[FCNT_OFF];
    if (n > MAXSLOT) n = MAXSLOT;
    if (slot >= n) return;
    int row   = ((const int*)ws)[FLIST_OFF + slot];
    int base  = blockIdx.x * 128;
    int wv    = threadIdx.x >> 6;
    int lane  = threadIdx.x & 63;
    float4 hv = *(const float4*)(h + (size_t)row * H_DIM + lane * 4);

    double best = 1e300;
    int    bi   = 1 << 30;
    for (int c = base + wv; c < base + 128; c += 4) {
        float4 cv = *(const float4*)(cb + (size_t)c * H_DIM + lane * 4);
        float dx = hv.x - cv.x, dy = hv.y - cv.y, dz = hv.z - cv.z, dw = hv.w - cv.w;
        double s = (double)dx * dx + (double)dy * dy + (double)dz * dz + (double)dw * dw;
        #pragma unroll
        for (int off = 32; off > 0; off >>= 1) s += __shfl_down(s, off, 64);
        if (lane == 0 && s < best) { best = s; bi = c; }
    }
    __shared__ double sb[4];
    __shared__ int    si[4];
    if (lane == 0) { sb[wv] = best; si[wv] = bi; }
    __syncthreads();
    if (threadIdx.x == 0) {
        double b = sb[0]; int x = si[0];
        for (int t = 1; t < 4; t++)
            if (sb[t] < b || (sb[t] == b && si[t] < x)) { b = sb[t]; x = si[t]; }
        fbest[slot * 64 + blockIdx.x] = b;
        fidx [slot * 64 + blockIdx.x] = x;
    }
}

__global__ __launch_bounds__(64) void fixup_final(float* __restrict__ ws,
                                                  const double* __restrict__ fbest,
                                                  const int* __restrict__ fidx) {
    int slot = blockIdx.x;
    int n = ((const int*)ws)[FCNT_OFF];
    if (n > MAXSLOT) n = MAXSLOT;
    if (slot >= n) return;
    int lane = threadIdx.x;
    double b = fbest[slot * 64 + lane];
    int    x = fidx [slot * 64 + lane];
    #pragma unroll
    for (int off = 32; off > 0; off >>= 1) {
        double ob = __shfl_down(b, off, 64);
        int    oi = __shfl_down(x, off, 64);
        if (ob < b || (ob == b && oi < x)) { b = ob; x = oi; }
    }
    if (lane == 0) {
        int row = ((const int*)ws)[FLIST_OFF + slot];
        ws[DISTF_OFF + row] = (float)b;
        ((int*)ws)[IDXF_OFF + row] = x;
    }
}

// ---------------------------------------------------------------------------
// B: after hipMemsetAsync zeroes d_out at fill rate, scatter 8192 ones + losses.
__global__ __launch_bounds__(256) void scatter_kernel(const float* __restrict__ ws,
                                                      float* __restrict__ out) {
    int row = blockIdx.x * 256 + threadIdx.x;   // 0..8191
    int bi  = ((const int*)ws)[IDXF_OFF + row];
    out[(size_t)row * K_CODES + bi] = 1.0f;
    out[(size_t)N_ROWS * K_CODES + row] = (1.25f / 256.f) * ws[DISTF_OFF + row];
}

// ---------------------------------------------------------------------------
extern "C" void kernel_launch(void* const* d_in, const int* in_sizes, int n_in,
                              void* d_out, int out_size, void* d_ws, size_t ws_size,
                              hipStream_t stream) {
    const float* h  = (const float*)d_in[0];
    const float* cb = (const float*)d_in[2];
    float* out = (float*)d_out;
    float* ws  = (float*)d_ws;
    char*  pk  = (char*)d_out;

    float*  pbest = (float*)(pk + PART_BEST);
    float*  psec  = (float*)(pk + PART_SEC);
    int*    pidx  = (int*)(pk + PART_IDX);
    double* fbest = (double*)(pk + FIXP_BEST);
    int*    fidx  = (int*)(pk + FIXP_IDX);

    prep_sq<<<4096, 256, 0, stream>>>(h, cb, ws);
    pack_kernel<<<2048, 256, 0, stream>>>(h, cb, pk);
    vq_min_kernel<<<dim3(N_ROWS / 128, NSPLIT), 256, 0, stream>>>(pk, ws, pbest, psec, pidx);
    merge_kernel<<<N_ROWS / 256, 256, 0, stream>>>(pbest, psec, pidx, ws);
    fixup_part<<<dim3(64, MAXSLOT), 256, 0, stream>>>(h, cb, ws, fbest, fidx);
    fixup_final<<<MAXSLOT, 64, 0, stream>>>(ws, fbest, fidx);
    // Zero the 256 MiB one-hot at memset fill rate, then scatter ones + losses.
    // (Stream-ordered: pk scratch in d_out is dead by this point.)
    hipMemsetAsync(d_out, 0, (size_t)out_size * sizeof(float), stream);
    scatter_kernel<<<N_ROWS / 256, 256, 0, stream>>>(ws, out);
}

// Round 12
// 425.695 us; speedup vs baseline: 1.4398x; 1.0001x over previous
//
#include <hip/hip_runtime.h>
#include <hip/hip_bf16.h>
#include <math.h>

// Problem constants (fixed by the reference).
#define N_ROWS   8192
#define K_CODES  8192
#define H_DIM    256
#define NSPLIT   16                   // 512 codes per split-column
#define KSPLIT   (K_CODES / NSPLIT)
// 3-term decomposition (ah·bh + al·bh + ah·bl): dot err ~2e-5; MARGIN 25x that.
// (R10 lesson: 2-term needs MARGIN 4e-2 -> ~270 flagged rows -> fixup costs
// more than the dropped MFMA saves. 3-term + 5e-4 -> ~3-10 flagged.)
#define MARGIN   5e-4f

typedef short short8 __attribute__((ext_vector_type(8)));
typedef float f32x4  __attribute__((ext_vector_type(4)));

// Workspace layout (float offsets). Head (C2..FCNT) is zeroed by memset each
// launch; C2/H2 are accumulated via fp32 atomics from pack_kernel.
#define C2_OFF      0
#define H2_OFF      8192
#define DISTF_OFF   16384
#define IDXF_OFF    (DISTF_OFF + 8192)
#define FCNT_OFF    (IDXF_OFF + 8192)         // int, at float index 32768
#define FLIST_OFF   (FCNT_OFF + 16)           // int[64]
#define MAXSLOT     64
#define WS_ZERO_BYTES ((size_t)(FLIST_OFF + MAXSLOT) * 4)

// d_out scratch map (memset+scatter rebuild d_out at the end):
//   [0,16M): packed bf16 hi/lo fragment arrays
//   [16M,+): per-split tracker partials, then fixup partials
// Pack layout: per (panel p of 16 rows, chunk c of 32 k): 64 lanes x 16 B;
// lane=(kg<<4)|ln15 holds row p*16+ln15, k=c*32+kg*8..+7.
// Segment address = ((p*8+c)*64+lane)*16 bytes.
#define PK_AHI ((size_t)0)
#define PK_ALO ((size_t)4 << 20)
#define PK_BHI ((size_t)8 << 20)
#define PK_BLO ((size_t)12 << 20)
#define PART_BEST ((size_t)16 << 20)
#define PART_SEC  (PART_BEST + (size_t)(NSPLIT * N_ROWS * 4))
#define PART_IDX  (PART_SEC  + (size_t)(NSPLIT * N_ROWS * 4))
#define FIXP_BEST (PART_IDX  + (size_t)(NSPLIT * N_ROWS * 4))   // double[64][64]
#define FIXP_IDX  (FIXP_BEST + (size_t)(MAXSLOT * 64 * 8))      // int[64][64]

// ---------------------------------------------------------------------------
__device__ __forceinline__ void async_copy16(const void* g, void* l) {
    __builtin_amdgcn_global_load_lds(
        (const __attribute__((address_space(1))) unsigned int*)g,
        (__attribute__((address_space(3))) unsigned int*)l, 16, 0, 0);
}

// fp32 -> bf16 hi/lo split, two elements at a time (RNE both; residual ~exact).
__device__ __forceinline__ void conv2(float a, float b, unsigned& hi, unsigned& lo) {
    float2 p0 = make_float2(a, b);
    __hip_bfloat162 hb = __float22bfloat162_rn(p0);
    unsigned h = *(unsigned*)&hb;
    hi = h;
    float ra = a - __uint_as_float(h << 16);
    float rb = b - __uint_as_float(h & 0xFFFF0000u);
    float2 p1 = make_float2(ra, rb);
    __hip_bfloat162 lb = __float22bfloat162_rn(p1);
    lo = *(unsigned*)&lb;
}

// ---------------------------------------------------------------------------
// Pack h and cb into hi/lo bf16 fragment-order arrays AND accumulate squared
// norms (fused R12: saves the prep_sq 24 MB re-read). One (panel,chunk)/wave.
// Norm atomic order varies run-to-run (~1 ulp ~2e-6) — far below MARGIN, and
// near-ties are re-resolved in fp64 fixup, so argmin stays deterministic.
__global__ __launch_bounds__(256) void pack_kernel(const float* __restrict__ h,
                                                   const float* __restrict__ cb,
                                                   char* __restrict__ out,
                                                   float* __restrict__ ws) {
    int w    = threadIdx.x >> 6;
    int lane = threadIdx.x & 63;
    int ln15 = lane & 15;
    int kg   = lane >> 4;
    bool isB = blockIdx.x >= 1024;
    int u = ((blockIdx.x & 1023) << 2) + w;      // 0..4095 (panel*8 + chunk)
    int p = u >> 3, c = u & 7;
    const float* src = isB ? cb : h;
    char* hiB = out + (isB ? PK_BHI : PK_AHI);
    char* loB = out + (isB ? PK_BLO : PK_ALO);
    const float* s = src + (size_t)(p * 16 + ln15) * H_DIM + c * 32 + kg * 8;
    float4 v0 = *(const float4*)s;
    float4 v1 = *(const float4*)(s + 4);
    unsigned h0, h1, h2, h3, l0, l1, l2, l3;
    conv2(v0.x, v0.y, h0, l0);
    conv2(v0.z, v0.w, h1, l1);
    conv2(v1.x, v1.y, h2, l2);
    conv2(v1.z, v1.w, h3, l3);
    size_t off = ((size_t)u * 64 + lane) * 16;
    *(uint4*)(hiB + off) = make_uint4(h0, h1, h2, h3);
    *(uint4*)(loB + off) = make_uint4(l0, l1, l2, l3);

    // Fused squared-norm partial: sum over this lane's 8 elems, reduce the 4
    // kg-lanes of the same row, one atomicAdd per (row, chunk).
    float sq = v0.x*v0.x + v0.y*v0.y + v0.z*v0.z + v0.w*v0.w
             + v1.x*v1.x + v1.y*v1.y + v1.z*v1.z + v1.w*v1.w;
    sq += __shfl_xor(sq, 16, 64);
    sq += __shfl_xor(sq, 32, 64);
    if (kg == 0) {
        int row = p * 16 + ln15;
        atomicAdd(&ws[(isB ? C2_OFF : H2_OFF) + row], sq);
    }
}

// ---------------------------------------------------------------------------
// A: 3-term MFMA GEMM-min (R8/R11 structure, measured-best & proven).
// 4 waves of 64x64; block = 128 rows x 128 codes per ct, ct x4 over the split.
// LDS 32K staging (1 KB segments, lane*16 reads: conflict-free) + 3K merge.
// ~940 TF effective = the m97-structure plateau; source-level pipelining
// attempts on this structure are documented neutral-to-regressive.
__global__ __launch_bounds__(256, 4) void vq_min_kernel(const char* __restrict__ pk,
                                                        const float* __restrict__ c2g,
                                                        float* __restrict__ pbest,
                                                        float* __restrict__ psec,
                                                        int* __restrict__ pidx) {
    __shared__ __align__(16) char smem[35840];
    const int tid  = threadIdx.x;
    const int w    = tid >> 6;
    const int lane = tid & 63;
    const int ln15 = lane & 15;
    const int kg   = lane >> 4;
    const int wm   = (w >> 1) * 64;      // wave row offset
    const int wn   = (w & 1) * 64;       // wave col offset
    const int am   = (w >> 1) * 4;       // local A panel base
    const int bn4  = (w & 1) * 4;        // local B panel base

    const int rowpan0 = blockIdx.x * 8;       // 8 panels = 128 rows
    const int bpan0   = blockIdx.y * (KSPLIT / 16);

    const size_t pkoff = (w == 0) ? PK_AHI : (w == 1) ? PK_ALO : (w == 2) ? PK_BHI : PK_BLO;
    char* lwave = smem + w * 8192;

    float best16[16], sec16[16];
    int   idx16[16];
    #pragma unroll
    for (int t = 0; t < 16; t++) { best16[t] = 3.4e38f; sec16[t] = 3.4e38f; idx16[t] = 0; }

    #pragma unroll 1
    for (int ct = 0; ct < KSPLIT / 128; ++ct) {
        const int kb   = blockIdx.y * KSPLIT + ct * 128;
        const int pan0 = (w < 2) ? rowpan0 : (bpan0 + ct * 8);
        f32x4 acc[4][4];
        #pragma unroll
        for (int i = 0; i < 4; i++)
            #pragma unroll
            for (int j = 0; j < 4; j++) acc[i][j] = (f32x4){0.f, 0.f, 0.f, 0.f};

        #pragma unroll 1
        for (int kc = 0; kc < 8; ++kc) {
            __syncthreads();                     // prior readers done before overwrite
            #pragma unroll
            for (int q = 0; q < 8; ++q) {
                const char* g = pk + pkoff + (((size_t)(pan0 + q) * 8 + kc) * 64 + lane) * 16;
                async_copy16(g, lwave + q * 1024);
            }
            __syncthreads();                     // drains vmcnt for global_load_lds

            short8 ah[4], al[4], bh[4], bl[4];
            #pragma unroll
            for (int i = 0; i < 4; i++) {
                int o = ((am + i) * 64 + lane) * 16;
                ah[i] = *(const short8*)(smem + o);
                al[i] = *(const short8*)(smem + 8192 + o);
            }
            #pragma unroll
            for (int j = 0; j < 4; j++) {
                int o = ((bn4 + j) * 64 + lane) * 16;
                bh[j] = *(const short8*)(smem + 16384 + o);
                bl[j] = *(const short8*)(smem + 24576 + o);
            }
            #pragma unroll
            for (int i = 0; i < 4; i++)
                #pragma unroll
                for (int j = 0; j < 4; j++) {
                    acc[i][j] = __builtin_amdgcn_mfma_f32_16x16x32_bf16(ah[i], bh[j], acc[i][j], 0, 0, 0);
                    acc[i][j] = __builtin_amdgcn_mfma_f32_16x16x32_bf16(al[i], bh[j], acc[i][j], 0, 0, 0);
                    acc[i][j] = __builtin_amdgcn_mfma_f32_16x16x32_bf16(ah[i], bl[j], acc[i][j], 0, 0, 0);
                }
        }

        // distances + tracker update (k strictly ascending within a lane)
        float cv[4];
        #pragma unroll
        for (int j = 0; j < 4; j++) cv[j] = c2g[kb + wn + j * 16 + ln15];
        #pragma unroll
        for (int i = 0; i < 4; i++)
            #pragma unroll
            for (int reg = 0; reg < 4; reg++) {
                const int t = i * 4 + reg;
                #pragma unroll
                for (int j = 0; j < 4; j++) {
                    float d = cv[j] - 2.f * acc[i][j][reg];
                    int   k = kb + wn + j * 16 + ln15;
                    if (d < best16[t])      { sec16[t] = best16[t]; best16[t] = d; idx16[t] = k; }
                    else if (d < sec16[t])  { sec16[t] = d; }
                }
            }
    }

    // Cross-lane merge over ln15 (butterfly within 16-lane kg group).
    #pragma unroll
    for (int t = 0; t < 16; t++) {
        float b = best16[t], s2 = sec16[t];
        int   bi = idx16[t];
        #pragma unroll
        for (int m = 1; m <= 8; m <<= 1) {
            float ob = __shfl_xor(b, m, 64);
            float os = __shfl_xor(s2, m, 64);
            int   oi = __shfl_xor(bi, m, 64);
            if (ob < b)      { s2 = fminf(b, os); b = ob; bi = oi; }
            else if (ob > b) { s2 = fminf(s2, ob); }
            else             { if (oi < bi) bi = oi; s2 = b; }
        }
        best16[t] = b; sec16[t] = s2; idx16[t] = bi;
    }
    // Two column-halves per row -> small LDS merge region (above staging).
    float* mb = (float*)(smem + 32768);
    float* ms = (float*)(smem + 32768 + 1024);
    int*   mi = (int*)(smem + 32768 + 2048);
    if (ln15 == 0) {
        #pragma unroll
        for (int i = 0; i < 4; i++)
            #pragma unroll
            for (int reg = 0; reg < 4; reg++) {
                int r = wm + i * 16 + kg * 4 + reg;
                int half = (w & 1);
                mb[r * 2 + half] = best16[i * 4 + reg];
                ms[r * 2 + half] = sec16[i * 4 + reg];
                mi[r * 2 + half] = idx16[i * 4 + reg];
            }
    }
    __syncthreads();
    if (tid < 128) {
        float b  = mb[tid * 2],     s2 = ms[tid * 2];
        int   bi = mi[tid * 2];
        float ob = mb[tid * 2 + 1], os = ms[tid * 2 + 1];
        int   oi = mi[tid * 2 + 1];
        if (ob < b)      { s2 = fminf(b, os); b = ob; bi = oi; }
        else if (ob > b) { s2 = fminf(s2, ob); }
        else             { if (oi < bi) bi = oi; s2 = b; }
        int row = blockIdx.x * 128 + tid;
        int s   = blockIdx.y;
        pbest[s * N_ROWS + row] = b;
        psec [s * N_ROWS + row] = s2;
        pidx [s * N_ROWS + row] = bi;
    }
}

// ---------------------------------------------------------------------------
__global__ __launch_bounds__(256) void merge_kernel(const float* __restrict__ pbest,
                                                    const float* __restrict__ psec,
                                                    const int* __restrict__ pidx,
                                                    float* __restrict__ ws) {
    int row = blockIdx.x * blockDim.x + threadIdx.x;
    if (row >= N_ROWS) return;
    float b  = pbest[row];
    float s2 = psec[row];
    int   bi = pidx[row];
    for (int s = 1; s < NSPLIT; s++) {
        float ob = pbest[s * N_ROWS + row];
        float os = psec [s * N_ROWS + row];
        int   oi = pidx [s * N_ROWS + row];
        if (ob < b)      { s2 = fminf(b, os); b = ob; bi = oi; }
        else if (ob > b) { s2 = fminf(s2, ob); }
        else             { if (oi < bi) bi = oi; s2 = b; }
    }
    float h2 = ws[H2_OFF + row];
    ws[DISTF_OFF + row] = h2 + b;
    ((int*)ws)[IDXF_OFF + row] = bi;
    if (s2 - b <= MARGIN) {
        int slot = atomicAdd(&((int*)ws)[FCNT_OFF], 1);
        if (slot < MAXSLOT) ((int*)ws)[FLIST_OFF + slot] = row;
    }
}

// ---------------------------------------------------------------------------
__global__ __launch_bounds__(256) void fixup_part(const float* __restrict__ h,
                                                  const float* __restrict__ cb,
                                                  float* __restrict__ ws,
                                                  double* __restrict__ fbest,
                                                  int* __restrict__ fidx) {
    int slot = blockIdx.y;
    int n = ((const int*)ws)[FCNT_OFF];
    if (n > MAXSLOT) n = MAXSLOT;
    if (slot >= n) return;
    int row   = ((const int*)ws)[FLIST_OFF + slot];
    int base  = blockIdx.x * 128;
    int wv    = threadIdx.x >> 6;
    int lane  = threadIdx.x & 63;
    float4 hv = *(const float4*)(h + (size_t)row * H_DIM + lane * 4);

    double best = 1e300;
    int    bi   = 1 << 30;
    for (int c = base + wv; c < base + 128; c += 4) {
        float4 cv = *(const float4*)(cb + (size_t)c * H_DIM + lane * 4);
        float dx = hv.x - cv.x, dy = hv.y - cv.y, dz = hv.z - cv.z, dw = hv.w - cv.w;
        double s = (double)dx * dx + (double)dy * dy + (double)dz * dz + (double)dw * dw;
        #pragma unroll
        for (int off = 32; off > 0; off >>= 1) s += __shfl_down(s, off, 64);
        if (lane == 0 && s < best) { best = s; bi = c; }
    }
    __shared__ double sb[4];
    __shared__ int    si[4];
    if (lane == 0) { sb[wv] = best; si[wv] = bi; }
    __syncthreads();
    if (threadIdx.x == 0) {
        double b = sb[0]; int x = si[0];
        for (int t = 1; t < 4; t++)
            if (sb[t] < b || (sb[t] == b && si[t] < x)) { b = sb[t]; x = si[t]; }
        fbest[slot * 64 + blockIdx.x] = b;
        fidx [slot * 64 + blockIdx.x] = x;
    }
}

__global__ __launch_bounds__(64) void fixup_final(float* __restrict__ ws,
                                                  const double* __restrict__ fbest,
                                                  const int* __restrict__ fidx) {
    int slot = blockIdx.x;
    int n = ((const int*)ws)[FCNT_OFF];
    if (n > MAXSLOT) n = MAXSLOT;
    if (slot >= n) return;
    int lane = threadIdx.x;
    double b = fbest[slot * 64 + lane];
    int    x = fidx [slot * 64 + lane];
    #pragma unroll
    for (int off = 32; off > 0; off >>= 1) {
        double ob = __shfl_down(b, off, 64);
        int    oi = __shfl_down(x, off, 64);
        if (ob < b || (ob == b && oi < x)) { b = ob; x = oi; }
    }
    if (lane == 0) {
        int row = ((const int*)ws)[FLIST_OFF + slot];
        ws[DISTF_OFF + row] = (float)b;
        ((int*)ws)[IDXF_OFF + row] = x;
    }
}

// ---------------------------------------------------------------------------
// B: after hipMemsetAsync zeroes d_out at fill rate, scatter 8192 ones + losses.
__global__ __launch_bounds__(256) void scatter_kernel(const float* __restrict__ ws,
                                                      float* __restrict__ out) {
    int row = blockIdx.x * 256 + threadIdx.x;   // 0..8191
    int bi  = ((const int*)ws)[IDXF_OFF + row];
    out[(size_t)row * K_CODES + bi] = 1.0f;
    out[(size_t)N_ROWS * K_CODES + row] = (1.25f / 256.f) * ws[DISTF_OFF + row];
}

// ---------------------------------------------------------------------------
extern "C" void kernel_launch(void* const* d_in, const int* in_sizes, int n_in,
                              void* d_out, int out_size, void* d_ws, size_t ws_size,
                              hipStream_t stream) {
    const float* h  = (const float*)d_in[0];
    const float* cb = (const float*)d_in[2];
    float* out = (float*)d_out;
    float* ws  = (float*)d_ws;
    char*  pk  = (char*)d_out;

    float*  pbest = (float*)(pk + PART_BEST);
    float*  psec  = (float*)(pk + PART_SEC);
    int*    pidx  = (int*)(pk + PART_IDX);
    double* fbest = (double*)(pk + FIXP_BEST);
    int*    fidx  = (int*)(pk + FIXP_IDX);

    // Zero C2/H2 accumulators + FCNT/FLIST head (132 KB, ~1 us).
    hipMemsetAsync(d_ws, 0, WS_ZERO_BYTES, stream);
    pack_kernel<<<2048, 256, 0, stream>>>(h, cb, pk, ws);
    vq_min_kernel<<<dim3(N_ROWS / 128, NSPLIT), 256, 0, stream>>>(pk, ws, pbest, psec, pidx);
    merge_kernel<<<N_ROWS / 256, 256, 0, stream>>>(pbest, psec, pidx, ws);
    fixup_part<<<dim3(64, MAXSLOT), 256, 0, stream>>>(h, cb, ws, fbest, fidx);
    fixup_final<<<MAXSLOT, 64, 0, stream>>>(ws, fbest, fidx);
    // Zero the 256 MiB one-hot at memset fill rate, then scatter ones + losses.
    // (Stream-ordered: pk scratch in d_out is dead by this point.)
    hipMemsetAsync(d_out, 0, (size_t)out_size * sizeof(float), stream);
    scatter_kernel<<<N_ROWS / 256, 256, 0, stream>>>(ws, out);
}